// Round 4
// baseline (2417.818 us; speedup 1.0000x reference)
//
#include <hip/hip_runtime.h>
#include <math.h>

// Problem constants
#define N_IMAGE   128
#define N_CAPTION 32
#define N_REGION  36
#define N_WORD    24
#define EMBED     1024
#define EPSV      1e-8f

// Workspace layout (float offsets)
#define WS_W1 0            // 64*64 weight-normed out1 W
#define WS_W2 4096         // 64 weight-normed out2 row
#define WS_S  4160         // 32 captions * 24 words * 8 kernels
#define WS_QN 10304        // 32 captions * 24 words * 32 blocks

// ---------------------------------------------------------------------------
// Kernel 1: per-caption precompute (blocks 0..31) + weight-norm (block 32)
// ---------------------------------------------------------------------------
__global__ __launch_bounds__(256) void cap_prep_k(
    const float* __restrict__ captions, const int* __restrict__ depends,
    const float* __restrict__ mean_k, const float* __restrict__ prec_k,
    const float* __restrict__ v1, const float* __restrict__ g1v,
    const float* __restrict__ v2, const float* __restrict__ g2v,
    float* __restrict__ ws) {
  __shared__ __align__(16) float capT[24][132];
  __shared__ float partB[2304];   // 4 groups * 576
  __shared__ float wsL[24][25];
  __shared__ float adjL[24][24];

  const int tid = threadIdx.x;

  if (blockIdx.x == 32) {         // ---- weight-norm path ----
    if (tid < 64) {
      const int j = tid;
      float s = 0.f;
      for (int c0 = 0; c0 < 64; c0 += 4) {
        float4 x = *(const float4*)(v1 + j * 64 + c0);
        s += x.x * x.x + x.y * x.y + x.z * x.z + x.w * x.w;
      }
      const float sc = g1v[j] / sqrtf(s);
      for (int c0 = 0; c0 < 64; c0++) ws[WS_W1 + j * 64 + c0] = v1[j * 64 + c0] * sc;
      float s2 = 0.f;
      for (int c0 = 0; c0 < 64; c0++) { float x = v2[c0]; s2 += x * x; }
      ws[WS_W2 + j] = v2[j] * (g2v[0] / sqrtf(s2));
    }
    return;
  }

  const int c = blockIdx.x;
  const float* capC = captions + c * N_WORD * EMBED;

  // words_sim raw = cap @ cap^T, 4x4 register tiles, 4-way split-K
  const int g = tid / 36, t = tid % 36;
  const int i0 = (t / 6) * 4, j0 = (t % 6) * 4;
  const bool act = tid < 144;
  float acc[4][4] = {};
  for (int k0 = 0; k0 < EMBED; k0 += 128) {
    for (int idx = tid; idx < 24 * 32; idx += 256) {
      int r = idx >> 5, q = idx & 31;
      *(float4*)&capT[r][q * 4] = *(const float4*)(capC + r * EMBED + k0 + q * 4);
    }
    __syncthreads();
    if (act) {
#pragma unroll
      for (int q8 = 0; q8 < 8; q8++) {
        const int q = g * 8 + q8;
        float4 av[4], bv[4];
#pragma unroll
        for (int a = 0; a < 4; a++) av[a] = *(const float4*)&capT[i0 + a][q * 4];
#pragma unroll
        for (int b = 0; b < 4; b++) bv[b] = *(const float4*)&capT[j0 + b][q * 4];
#pragma unroll
        for (int a = 0; a < 4; a++)
#pragma unroll
          for (int b = 0; b < 4; b++)
            acc[a][b] += av[a].x * bv[b].x + av[a].y * bv[b].y +
                         av[a].z * bv[b].z + av[a].w * bv[b].w;
      }
    }
    __syncthreads();
  }
  if (act)
#pragma unroll
    for (int a = 0; a < 4; a++)
#pragma unroll
      for (int b = 0; b < 4; b++)
        partB[g * 576 + (i0 + a) * 24 + (j0 + b)] = acc[a][b];
  __syncthreads();
  for (int p = tid; p < 576; p += 256)
    wsL[p / 24][p % 24] = partB[p] + partB[p + 576] + partB[p + 1152] + partB[p + 1728];
  {
    float* ap = &adjL[0][0];
    for (int p = tid; p < 576; p += 256) ap[p] = 0.f;
  }
  __syncthreads();
  // row softmax with lambda=4
  if (tid < 24) {
    const int i = tid;
    float m = -1e30f;
    for (int j = 0; j < 24; j++) m = fmaxf(m, wsL[i][j]);
    float ssum = 0.f;
    for (int j = 0; j < 24; j++) {
      float e = expf(4.0f * (wsL[i][j] - m));
      wsL[i][j] = e; ssum += e;
    }
    float inv = 1.0f / ssum;
    for (int j = 0; j < 24; j++) wsL[i][j] *= inv;
  }
  __syncthreads();
  // adjacency scatter: pairs 1..22 valid (pair 0 skipped per reference)
  if (tid >= 1 && tid < 23) {
    int r = depends[c * 46 + tid * 2];
    int cc = depends[c * 46 + tid * 2 + 1];
    if ((unsigned)r < 24u && (unsigned)cc < 24u) {
      adjL[r][cc] = 1.f;
      adjL[cc][r] = 1.f;
    }
  }
  __syncthreads();
  if (tid < 24) adjL[tid][tid] += 1.f;  // + eye
  __syncthreads();
  // S[i][k] = sum_j adj[i,j] * kw_norm[i,j,k]
  if (tid < 24) {
    const int i = tid;
    float mk[8], pk2[8];
#pragma unroll
    for (int k = 0; k < 8; k++) {
      mk[k] = mean_k[k];
      float p = prec_k[k];
      pk2[k] = 1e-14f + p * p;
    }
    float s2 = 0.f;
    for (int j = 0; j < 24; j++) {
      float a = adjL[i][j] * wsL[i][j];
      s2 += a * a;
    }
    const float inv = 1.0f / (sqrtf(s2) + EPSV);
    float accS[8] = {};
    for (int j = 0; j < 24; j++) {
      const float adj_ij = adjL[i][j];
      if (adj_ij != 0.f) {
        const float nb = adj_ij * wsL[i][j] * inv;
        float wk[8], ssum = 0.f;
#pragma unroll
        for (int k = 0; k < 8; k++) {
          float d = nb - mk[k];
          wk[k] = expf(-0.5f * d * d / pk2[k]);
          ssum += wk[k];
        }
        const float invs = adj_ij / ssum;
#pragma unroll
        for (int k = 0; k < 8; k++) accS[k] += wk[k] * invs;
      }
    }
#pragma unroll
    for (int k = 0; k < 8; k++) ws[WS_S + (c * 24 + i) * 8 + k] = accS[k];
  }
  // qn[w][f]: block norms of caption words
  for (int p = tid; p < 768; p += 256) {
    const int w = p >> 5, f = p & 31;
    const float* q = capC + w * EMBED + f * 32;
    float s = 0.f;
#pragma unroll
    for (int d = 0; d < 32; d += 4) {
      float4 v = *(const float4*)(q + d);
      s += v.x * v.x + v.y * v.y + v.z * v.z + v.w * v.w;
    }
    ws[WS_QN + (c * 24 + w) * 32 + f] = sqrtf(s);
  }
}

// ---------------------------------------------------------------------------
// Kernel 2: main — one block per (image n, caption c); 39.6 KB LDS,
// __launch_bounds__(256,4) -> 4 blocks/CU, 16 waves/CU.
// XCD swizzle: n = (B&7) + 8*(B>>8), c = (B>>3)&31 — all 32 blocks of an
// image land on the same XCD (B%8) in consecutive dispatch order -> L2-hot.
// ---------------------------------------------------------------------------
__global__ __launch_bounds__(256, 4) void main_k(
    const float* __restrict__ images, const float* __restrict__ captions,
    const float* __restrict__ conv_w, const float* __restrict__ out1_b,
    const float* __restrict__ out2_b, const float* __restrict__ ws,
    float* __restrict__ out) {
  // bufA phases:
  //  S1 loop : IMG[36][132]@0          CAP[24][132]@4752
  //  S1 epi  : partB[3456]@0
  //  S2/S3   : IMG@0 (staged/chunk)    attnW[24][44]@4752 qn[768]@5808 tnode[24][36]@6576
  //  S4a     : convT[32][68]@0         (tnode read @6576)
  //  S4b     : W1t[64][68]@0
  __shared__ __align__(16) float bufA[7920];
  // bufB: attnL[36][25]@0 (S1/S2) -> hidden[24][68]@0 (S4); smallb@1632:
  //       w2@1632 b1@1696 Ss@1760 sred@1952
  __shared__ __align__(16) float bufB[1984];

  const int tid = threadIdx.x;
  const int B = blockIdx.x;
  const int n = (B & 7) + 8 * (B >> 8);
  const int c = (B >> 3) & 31;
  const float* imgN = images + n * N_REGION * EMBED;
  const float* capC = captions + c * N_WORD * EMBED;
  float* IMG = bufA;
  float* CAP = bufA + 4752;

  // ============ stage 1: attn logits = img @ cap^T ============
  // 216 threads: 4 split-K groups x 54 tiles; tile rows {r0+9a}, cols {w0+6b}
  // (strided so av/bv ds_read_b128 lanes spread across banks).
  const int g1 = tid / 54, t1 = tid % 54;
  const int r0 = t1 / 6, w0 = t1 % 6;
  const bool act1 = tid < 216;
  float acc[4][4] = {};
  for (int k0 = 0; k0 < EMBED; k0 += 128) {
    __syncthreads();
    for (int idx = tid; idx < 1920; idx += 256) {
      if (idx < 1152) {
        const int r = idx >> 5, q = idx & 31;
        *(float4*)&IMG[r * 132 + q * 4] = *(const float4*)(imgN + r * EMBED + k0 + q * 4);
      } else {
        const int j = idx - 1152, r = j >> 5, q = j & 31;
        *(float4*)&CAP[r * 132 + q * 4] = *(const float4*)(capC + r * EMBED + k0 + q * 4);
      }
    }
    __syncthreads();
    if (act1) {
#pragma unroll
      for (int q8 = 0; q8 < 8; q8++) {
        const int q = g1 * 8 + q8;
        float4 av[4], bv[4];
#pragma unroll
        for (int a = 0; a < 4; a++) av[a] = *(const float4*)&IMG[(r0 + 9 * a) * 132 + q * 4];
#pragma unroll
        for (int b = 0; b < 4; b++) bv[b] = *(const float4*)&CAP[(w0 + 6 * b) * 132 + q * 4];
#pragma unroll
        for (int a = 0; a < 4; a++)
#pragma unroll
          for (int b = 0; b < 4; b++)
            acc[a][b] += av[a].x * bv[b].x + av[a].y * bv[b].y +
                         av[a].z * bv[b].z + av[a].w * bv[b].w;
      }
    }
  }
  __syncthreads();
  {
    float* partB = bufA;        // IMG dead
    if (act1) {
#pragma unroll
      for (int a = 0; a < 4; a++)
#pragma unroll
        for (int b = 0; b < 4; b++)
          partB[g1 * 864 + (r0 + 9 * a) * 24 + (w0 + 6 * b)] = acc[a][b];
    }
    __syncthreads();
    for (int p = tid; p < 864; p += 256) {
      float s = partB[p] + partB[p + 864] + partB[p + 1728] + partB[p + 2592];
      bufB[(p / 24) * 25 + (p % 24)] = (s > 0.f) ? s : 0.1f * s;  // leaky_relu
    }
    __syncthreads();
  }

  // ============ stage 2: l2norm over words, softmax over regions ============
  float* attnL = bufB;            // [36][25]
  if (tid < 36) {
    const int r = tid;
    float s = 0.f;
    for (int w = 0; w < 24; w++) { float x = attnL[r * 25 + w]; s += x * x; }
    const float inv = 1.f / (sqrtf(s) + EPSV);
    for (int w = 0; w < 24; w++) attnL[r * 25 + w] *= inv;
  }
  __syncthreads();
  float* attnW = bufA + 4752;     // [24][44] (CAP dead)
  if (tid < 24) {
    const int w = tid;
    float m = -1e30f;
    for (int r = 0; r < 36; r++) m = fmaxf(m, attnL[r * 25 + w]);
    float ssum = 0.f;
    for (int r = 0; r < 36; r++) {
      float e = expf(4.0f * (attnL[r * 25 + w] - m));
      attnW[w * 44 + r] = e; ssum += e;
    }
    const float inv = 1.0f / ssum;
    for (int r = 0; r < 36; r++) attnW[w * 44 + r] *= inv;
  }
  float* qnL = bufA + 5808;       // [24][32]
  for (int p = tid; p < 768; p += 256) qnL[p] = ws[WS_QN + c * 768 + p];
  // visibility: first __syncthreads inside stage-3 loop

  // ============ stage 3: register wctx + fused block-cosine -> tnode ============
  float* tnodeL = bufA + 6576;    // [24][36]
  const int g3 = tid >> 5, dq = tid & 31, w03 = g3 * 4;
  for (int k0 = 0; k0 < EMBED; k0 += 128) {
    __syncthreads();
    for (int idx = tid; idx < 1152; idx += 256) {   // IMG only
      const int r = idx >> 5, q = idx & 31;
      *(float4*)&IMG[r * 132 + q * 4] = *(const float4*)(imgN + r * EMBED + k0 + q * 4);
    }
    __syncthreads();
    if (tid < 192) {
      float4 ctx0 = make_float4(0.f, 0.f, 0.f, 0.f), ctx1 = ctx0, ctx2 = ctx0, ctx3 = ctx0;
      for (int rb = 0; rb < 36; rb += 4) {
        float4 iv0 = *(const float4*)&IMG[(rb + 0) * 132 + dq * 4];
        float4 iv1 = *(const float4*)&IMG[(rb + 1) * 132 + dq * 4];
        float4 iv2 = *(const float4*)&IMG[(rb + 2) * 132 + dq * 4];
        float4 iv3 = *(const float4*)&IMG[(rb + 3) * 132 + dq * 4];
        float4 a0 = *(const float4*)&attnW[(w03 + 0) * 44 + rb];
        float4 a1 = *(const float4*)&attnW[(w03 + 1) * 44 + rb];
        float4 a2 = *(const float4*)&attnW[(w03 + 2) * 44 + rb];
        float4 a3 = *(const float4*)&attnW[(w03 + 3) * 44 + rb];
        ctx0.x += a0.x * iv0.x + a0.y * iv1.x + a0.z * iv2.x + a0.w * iv3.x;
        ctx0.y += a0.x * iv0.y + a0.y * iv1.y + a0.z * iv2.y + a0.w * iv3.y;
        ctx0.z += a0.x * iv0.z + a0.y * iv1.z + a0.z * iv2.z + a0.w * iv3.z;
        ctx0.w += a0.x * iv0.w + a0.y * iv1.w + a0.z * iv2.w + a0.w * iv3.w;
        ctx1.x += a1.x * iv0.x + a1.y * iv1.x + a1.z * iv2.x + a1.w * iv3.x;
        ctx1.y += a1.x * iv0.y + a1.y * iv1.y + a1.z * iv2.y + a1.w * iv3.y;
        ctx1.z += a1.x * iv0.z + a1.y * iv1.z + a1.z * iv2.z + a1.w * iv3.z;
        ctx1.w += a1.x * iv0.w + a1.y * iv1.w + a1.z * iv2.w + a1.w * iv3.w;
        ctx2.x += a2.x * iv0.x + a2.y * iv1.x + a2.z * iv2.x + a2.w * iv3.x;
        ctx2.y += a2.x * iv0.y + a2.y * iv1.y + a2.z * iv2.y + a2.w * iv3.y;
        ctx2.z += a2.x * iv0.z + a2.y * iv1.z + a2.z * iv2.z + a2.w * iv3.z;
        ctx2.w += a2.x * iv0.w + a2.y * iv1.w + a2.z * iv2.w + a2.w * iv3.w;
        ctx3.x += a3.x * iv0.x + a3.y * iv1.x + a3.z * iv2.x + a3.w * iv3.x;
        ctx3.y += a3.x * iv0.y + a3.y * iv1.y + a3.z * iv2.y + a3.w * iv3.y;
        ctx3.z += a3.x * iv0.z + a3.y * iv1.z + a3.z * iv2.z + a3.w * iv3.z;
        ctx3.w += a3.x * iv0.w + a3.y * iv1.w + a3.z * iv2.w + a3.w * iv3.w;
      }
      // cosine partials: cap straight from global (L2-hot)
      float red[8];
      {
        float4 c4;
        c4 = *(const float4*)(capC + (w03 + 0) * EMBED + k0 + dq * 4);
        red[0] = c4.x * ctx0.x + c4.y * ctx0.y + c4.z * ctx0.z + c4.w * ctx0.w;
        red[4] = ctx0.x * ctx0.x + ctx0.y * ctx0.y + ctx0.z * ctx0.z + ctx0.w * ctx0.w;
        c4 = *(const float4*)(capC + (w03 + 1) * EMBED + k0 + dq * 4);
        red[1] = c4.x * ctx1.x + c4.y * ctx1.y + c4.z * ctx1.z + c4.w * ctx1.w;
        red[5] = ctx1.x * ctx1.x + ctx1.y * ctx1.y + ctx1.z * ctx1.z + ctx1.w * ctx1.w;
        c4 = *(const float4*)(capC + (w03 + 2) * EMBED + k0 + dq * 4);
        red[2] = c4.x * ctx2.x + c4.y * ctx2.y + c4.z * ctx2.z + c4.w * ctx2.w;
        red[6] = ctx2.x * ctx2.x + ctx2.y * ctx2.y + ctx2.z * ctx2.z + ctx2.w * ctx2.w;
        c4 = *(const float4*)(capC + (w03 + 3) * EMBED + k0 + dq * 4);
        red[3] = c4.x * ctx3.x + c4.y * ctx3.y + c4.z * ctx3.z + c4.w * ctx3.w;
        red[7] = ctx3.x * ctx3.x + ctx3.y * ctx3.y + ctx3.z * ctx3.z + ctx3.w * ctx3.w;
      }
      // butterfly over the 8-lane octet owning this (word-group, f-block)
#pragma unroll
      for (int m = 1; m < 8; m <<= 1) {
#pragma unroll
        for (int t = 0; t < 8; t++) red[t] += __shfl_xor(red[t], m);
      }
      if ((dq & 7) == 0) {
        const int f = (k0 >> 5) + (dq >> 3);
#pragma unroll
        for (int j = 0; j < 4; j++) {
          const float qn = qnL[(w03 + j) * 32 + f];
          tnodeL[(w03 + j) * 36 + f] = red[j] / fmaxf(qn * sqrtf(red[4 + j]), EPSV);
        }
      }
    }
  }
  __syncthreads();

  // ============ stage 4a: conv collapse -> hidden ============
  float* convT = bufA;            // [32 f][68]: convT[f][col], col=k*8+o (IMG dead)
  for (int idx = tid; idx < 2048; idx += 256) {
    const int f = idx >> 6, col = idx & 63;
    convT[f * 68 + col] = conv_w[(col >> 3) * 256 + f * 8 + (col & 7)];
  }
  float* w2s = bufB + 1632, * b1s = bufB + 1696, * Ss = bufB + 1760, * sred = bufB + 1952;
  for (int p = tid; p < 192; p += 256) Ss[p] = ws[WS_S + c * 192 + p];
  if (tid < 64) w2s[tid] = ws[WS_W2 + tid];
  else if (tid < 128) b1s[tid - 64] = out1_b[tid - 64];
  __syncthreads();

  float* hiddenL = bufB;          // [24][68] (attnL dead)
  {
    const int col = tid & 63, wg = tid >> 6;
    float cw[32];
#pragma unroll
    for (int f = 0; f < 32; f++) cw[f] = convT[f * 68 + col];
    const int kk = col >> 3;
#pragma unroll
    for (int rnd = 0; rnd < 6; rnd++) {
      const int w = wg * 6 + rnd;
      float a = 0.f;
#pragma unroll
      for (int f4 = 0; f4 < 8; f4++) {
        float4 t4 = *(const float4*)&tnodeL[w * 36 + f4 * 4];
        a += t4.x * cw[f4 * 4 + 0] + t4.y * cw[f4 * 4 + 1] +
             t4.z * cw[f4 * 4 + 2] + t4.w * cw[f4 * 4 + 3];
      }
      hiddenL[w * 68 + col] = Ss[w * 8 + kk] * a;
    }
  }
  __syncthreads();

  // ============ stage 4b: h = tanh(hidden @ W1^T + b1) ============
  float* W1t = bufA;              // [64 col][68]: W1t[col][j] (convT/tnode dead)
  for (int idx = tid; idx < 4096; idx += 256) {
    const int j = idx >> 6, col = idx & 63;
    W1t[col * 68 + j] = ws[WS_W1 + idx];
  }
  __syncthreads();
  float hv[2][4];
  {
    int pc = 0;
    for (int p = tid; p < 384; p += 256, pc++) {
      const int w = p >> 4, j0 = (p & 15) * 4;
      float ax = b1s[j0 + 0], ay = b1s[j0 + 1], az = b1s[j0 + 2], aww = b1s[j0 + 3];
      for (int col = 0; col < 64; col += 4) {
        float4 h4 = *(const float4*)&hiddenL[w * 68 + col];
        float4 wv0 = *(const float4*)&W1t[(col + 0) * 68 + j0];
        float4 wv1 = *(const float4*)&W1t[(col + 1) * 68 + j0];
        float4 wv2 = *(const float4*)&W1t[(col + 2) * 68 + j0];
        float4 wv3 = *(const float4*)&W1t[(col + 3) * 68 + j0];
        ax  += h4.x * wv0.x + h4.y * wv1.x + h4.z * wv2.x + h4.w * wv3.x;
        ay  += h4.x * wv0.y + h4.y * wv1.y + h4.z * wv2.y + h4.w * wv3.y;
        az  += h4.x * wv0.z + h4.y * wv1.z + h4.z * wv2.z + h4.w * wv3.z;
        aww += h4.x * wv0.w + h4.y * wv1.w + h4.z * wv2.w + h4.w * wv3.w;
      }
      hv[pc][0] = tanhf(ax); hv[pc][1] = tanhf(ay);
      hv[pc][2] = tanhf(az); hv[pc][3] = tanhf(aww);
    }
    __syncthreads();
    pc = 0;
    for (int p = tid; p < 384; p += 256, pc++) {
      const int w = p >> 4, j0 = (p & 15) * 4;
      hiddenL[w * 68 + j0 + 0] = hv[pc][0]; hiddenL[w * 68 + j0 + 1] = hv[pc][1];
      hiddenL[w * 68 + j0 + 2] = hv[pc][2]; hiddenL[w * 68 + j0 + 3] = hv[pc][3];
    }
    __syncthreads();
  }

  // s[w] = h[w]·w2 + b2; output = mean over words
  if (tid < 24) {
    const int w = tid;
    float sv = out2_b[0];
    for (int j = 0; j < 64; j++) sv += hiddenL[w * 68 + j] * w2s[j];
    sred[w] = sv;
  }
  __syncthreads();
  if (tid == 0) {
    float s = 0.f;
    for (int w = 0; w < 24; w++) s += sred[w];
    out[n * 32 + c] = s * (1.0f / 24.0f);
  }
}

// ---------------------------------------------------------------------------
extern "C" void kernel_launch(void* const* d_in, const int* in_sizes, int n_in,
                              void* d_out, int out_size, void* d_ws, size_t ws_size,
                              hipStream_t stream) {
  const float* images   = (const float*)d_in[0];
  const float* captions = (const float*)d_in[1];
  const int*   depends  = (const int*)d_in[2];
  // d_in[3] cap_lens: unused (all == N_WORD)
  const float* mean_k   = (const float*)d_in[4];
  const float* prec_k   = (const float*)d_in[5];
  const float* conv_w   = (const float*)d_in[6];
  const float* out1_v   = (const float*)d_in[7];
  const float* out1_g   = (const float*)d_in[8];
  const float* out1_b   = (const float*)d_in[9];
  const float* out2_v   = (const float*)d_in[10];
  const float* out2_g   = (const float*)d_in[11];
  const float* out2_b   = (const float*)d_in[12];
  float* ws  = (float*)d_ws;
  float* out = (float*)d_out;

  cap_prep_k<<<dim3(33), dim3(256), 0, stream>>>(
      captions, depends, mean_k, prec_k, out1_v, out1_g, out2_v, out2_g, ws);
  main_k<<<dim3(N_IMAGE * N_CAPTION), dim3(256), 0, stream>>>(
      images, captions, conv_w, out1_b, out2_b, ws, out);
}

// Round 5
// 1082.690 us; speedup vs baseline: 2.2332x; 2.2332x over previous
//
#include <hip/hip_runtime.h>
#include <math.h>

// Problem constants
#define N_IMAGE   128
#define N_CAPTION 32
#define N_REGION  36
#define N_WORD    24
#define EMBED     1024
#define EPSV      1e-8f

// Workspace layout (float offsets)
#define WS_W1 0            // 64*64 weight-normed out1 W
#define WS_W2 4096         // 64 weight-normed out2 row
#define WS_S  4160         // 32 captions * 24 words * 8 kernels
#define WS_QN 10304        // 32 captions * 24 words * 32 blocks

// ---------------------------------------------------------------------------
// Kernel 1: per-caption precompute (blocks 0..31) + weight-norm (block 32)
// ---------------------------------------------------------------------------
__global__ __launch_bounds__(256) void cap_prep_k(
    const float* __restrict__ captions, const int* __restrict__ depends,
    const float* __restrict__ mean_k, const float* __restrict__ prec_k,
    const float* __restrict__ v1, const float* __restrict__ g1v,
    const float* __restrict__ v2, const float* __restrict__ g2v,
    float* __restrict__ ws) {
  __shared__ __align__(16) float capT[24][132];
  __shared__ float partB[2304];   // 4 groups * 576
  __shared__ float wsL[24][25];
  __shared__ float adjL[24][24];

  const int tid = threadIdx.x;

  if (blockIdx.x == 32) {         // ---- weight-norm path ----
    if (tid < 64) {
      const int j = tid;
      float s = 0.f;
      for (int c0 = 0; c0 < 64; c0 += 4) {
        float4 x = *(const float4*)(v1 + j * 64 + c0);
        s += x.x * x.x + x.y * x.y + x.z * x.z + x.w * x.w;
      }
      const float sc = g1v[j] / sqrtf(s);
      for (int c0 = 0; c0 < 64; c0++) ws[WS_W1 + j * 64 + c0] = v1[j * 64 + c0] * sc;
      float s2 = 0.f;
      for (int c0 = 0; c0 < 64; c0++) { float x = v2[c0]; s2 += x * x; }
      ws[WS_W2 + j] = v2[j] * (g2v[0] / sqrtf(s2));
    }
    return;
  }

  const int c = blockIdx.x;
  const float* capC = captions + c * N_WORD * EMBED;

  // words_sim raw = cap @ cap^T, 4x4 register tiles, 4-way split-K
  const int g = tid / 36, t = tid % 36;
  const int i0 = (t / 6) * 4, j0 = (t % 6) * 4;
  const bool act = tid < 144;
  float acc[4][4] = {};
  for (int k0 = 0; k0 < EMBED; k0 += 128) {
    for (int idx = tid; idx < 24 * 32; idx += 256) {
      int r = idx >> 5, q = idx & 31;
      *(float4*)&capT[r][q * 4] = *(const float4*)(capC + r * EMBED + k0 + q * 4);
    }
    __syncthreads();
    if (act) {
#pragma unroll
      for (int q8 = 0; q8 < 8; q8++) {
        const int q = g * 8 + q8;
        float4 av[4], bv[4];
#pragma unroll
        for (int a = 0; a < 4; a++) av[a] = *(const float4*)&capT[i0 + a][q * 4];
#pragma unroll
        for (int b = 0; b < 4; b++) bv[b] = *(const float4*)&capT[j0 + b][q * 4];
#pragma unroll
        for (int a = 0; a < 4; a++)
#pragma unroll
          for (int b = 0; b < 4; b++)
            acc[a][b] += av[a].x * bv[b].x + av[a].y * bv[b].y +
                         av[a].z * bv[b].z + av[a].w * bv[b].w;
      }
    }
    __syncthreads();
  }
  if (act)
#pragma unroll
    for (int a = 0; a < 4; a++)
#pragma unroll
      for (int b = 0; b < 4; b++)
        partB[g * 576 + (i0 + a) * 24 + (j0 + b)] = acc[a][b];
  __syncthreads();
  for (int p = tid; p < 576; p += 256)
    wsL[p / 24][p % 24] = partB[p] + partB[p + 576] + partB[p + 1152] + partB[p + 1728];
  {
    float* ap = &adjL[0][0];
    for (int p = tid; p < 576; p += 256) ap[p] = 0.f;
  }
  __syncthreads();
  // row softmax with lambda=4
  if (tid < 24) {
    const int i = tid;
    float m = -1e30f;
    for (int j = 0; j < 24; j++) m = fmaxf(m, wsL[i][j]);
    float ssum = 0.f;
    for (int j = 0; j < 24; j++) {
      float e = expf(4.0f * (wsL[i][j] - m));
      wsL[i][j] = e; ssum += e;
    }
    float inv = 1.0f / ssum;
    for (int j = 0; j < 24; j++) wsL[i][j] *= inv;
  }
  __syncthreads();
  // adjacency scatter: pairs 1..22 valid (pair 0 skipped per reference)
  if (tid >= 1 && tid < 23) {
    int r = depends[c * 46 + tid * 2];
    int cc = depends[c * 46 + tid * 2 + 1];
    if ((unsigned)r < 24u && (unsigned)cc < 24u) {
      adjL[r][cc] = 1.f;
      adjL[cc][r] = 1.f;
    }
  }
  __syncthreads();
  if (tid < 24) adjL[tid][tid] += 1.f;  // + eye
  __syncthreads();
  // S[i][k] = sum_j adj[i,j] * kw_norm[i,j,k]
  if (tid < 24) {
    const int i = tid;
    float mk[8], pk2[8];
#pragma unroll
    for (int k = 0; k < 8; k++) {
      mk[k] = mean_k[k];
      float p = prec_k[k];
      pk2[k] = 1e-14f + p * p;
    }
    float s2 = 0.f;
    for (int j = 0; j < 24; j++) {
      float a = adjL[i][j] * wsL[i][j];
      s2 += a * a;
    }
    const float inv = 1.0f / (sqrtf(s2) + EPSV);
    float accS[8] = {};
    for (int j = 0; j < 24; j++) {
      const float adj_ij = adjL[i][j];
      if (adj_ij != 0.f) {
        const float nb = adj_ij * wsL[i][j] * inv;
        float wk[8], ssum = 0.f;
#pragma unroll
        for (int k = 0; k < 8; k++) {
          float d = nb - mk[k];
          wk[k] = expf(-0.5f * d * d / pk2[k]);
          ssum += wk[k];
        }
        const float invs = adj_ij / ssum;
#pragma unroll
        for (int k = 0; k < 8; k++) accS[k] += wk[k] * invs;
      }
    }
#pragma unroll
    for (int k = 0; k < 8; k++) ws[WS_S + (c * 24 + i) * 8 + k] = accS[k];
  }
  // qn[w][f]: block norms of caption words
  for (int p = tid; p < 768; p += 256) {
    const int w = p >> 5, f = p & 31;
    const float* q = capC + w * EMBED + f * 32;
    float s = 0.f;
#pragma unroll
    for (int d = 0; d < 32; d += 4) {
      float4 v = *(const float4*)(q + d);
      s += v.x * v.x + v.y * v.y + v.z * v.z + v.w * v.w;
    }
    ws[WS_QN + (c * 24 + w) * 32 + f] = sqrtf(s);
  }
}

// ---------------------------------------------------------------------------
// Kernel 2: main — one block per (image n, caption c); 39.6 KB LDS.
// R5: __launch_bounds__(256, 2) — R3/R4's (256,4) made the allocator clamp
// to 64 VGPRs and spill GB-scale scratch (WRITE_SIZE 4.65 GB). Cap 256 VGPRs
// guarantees no spill; LDS still allows up to 4 blocks/CU if regs permit.
// XCD swizzle: n = (B&7) + 8*(B>>8), c = (B>>3)&31 — all 32 blocks of an
// image land on the same XCD (B%8) in consecutive dispatch order -> L2-hot.
// ---------------------------------------------------------------------------
__global__ __launch_bounds__(256, 2) void main_k(
    const float* __restrict__ images, const float* __restrict__ captions,
    const float* __restrict__ conv_w, const float* __restrict__ out1_b,
    const float* __restrict__ out2_b, const float* __restrict__ ws,
    float* __restrict__ out) {
  // bufA phases:
  //  S1 loop : IMG[36][132]@0          CAP[24][132]@4752
  //  S1 epi  : partB[3456]@0
  //  S2/S3   : IMG@0 (staged/chunk)    attnW[24][44]@4752 qn[768]@5808 tnode[24][36]@6576
  //  S4a     : convT[32][68]@0         (tnode read @6576)
  //  S4b     : W1t[64][68]@0
  __shared__ __align__(16) float bufA[7920];
  // bufB: attnL[36][25]@0 (S1/S2) -> hidden[24][68]@0 (S4); smallb@1632:
  //       w2@1632 b1@1696 Ss@1760 sred@1952
  __shared__ __align__(16) float bufB[1984];

  const int tid = threadIdx.x;
  const int B = blockIdx.x;
  const int n = (B & 7) + 8 * (B >> 8);
  const int c = (B >> 3) & 31;
  const float* imgN = images + n * N_REGION * EMBED;
  const float* capC = captions + c * N_WORD * EMBED;
  float* IMG = bufA;
  float* CAP = bufA + 4752;

  // ============ stage 1: attn logits = img @ cap^T ============
  // 216 threads: 4 split-K groups x 54 tiles; tile rows {r0+9a}, cols {w0+6b}
  const int g1 = tid / 54, t1 = tid % 54;
  const int r0 = t1 / 6, w0 = t1 % 6;
  const bool act1 = tid < 216;
  float acc[4][4] = {};
  for (int k0 = 0; k0 < EMBED; k0 += 128) {
    __syncthreads();
    for (int idx = tid; idx < 1920; idx += 256) {
      if (idx < 1152) {
        const int r = idx >> 5, q = idx & 31;
        *(float4*)&IMG[r * 132 + q * 4] = *(const float4*)(imgN + r * EMBED + k0 + q * 4);
      } else {
        const int j = idx - 1152, r = j >> 5, q = j & 31;
        *(float4*)&CAP[r * 132 + q * 4] = *(const float4*)(capC + r * EMBED + k0 + q * 4);
      }
    }
    __syncthreads();
    if (act1) {
#pragma unroll
      for (int q8 = 0; q8 < 8; q8++) {
        const int q = g1 * 8 + q8;
        float4 av[4], bv[4];
#pragma unroll
        for (int a = 0; a < 4; a++) av[a] = *(const float4*)&IMG[(r0 + 9 * a) * 132 + q * 4];
#pragma unroll
        for (int b = 0; b < 4; b++) bv[b] = *(const float4*)&CAP[(w0 + 6 * b) * 132 + q * 4];
#pragma unroll
        for (int a = 0; a < 4; a++)
#pragma unroll
          for (int b = 0; b < 4; b++)
            acc[a][b] += av[a].x * bv[b].x + av[a].y * bv[b].y +
                         av[a].z * bv[b].z + av[a].w * bv[b].w;
      }
    }
  }
  __syncthreads();
  {
    float* partB = bufA;        // IMG dead
    if (act1) {
#pragma unroll
      for (int a = 0; a < 4; a++)
#pragma unroll
        for (int b = 0; b < 4; b++)
          partB[g1 * 864 + (r0 + 9 * a) * 24 + (w0 + 6 * b)] = acc[a][b];
    }
    __syncthreads();
    for (int p = tid; p < 864; p += 256) {
      float s = partB[p] + partB[p + 864] + partB[p + 1728] + partB[p + 2592];
      bufB[(p / 24) * 25 + (p % 24)] = (s > 0.f) ? s : 0.1f * s;  // leaky_relu
    }
    __syncthreads();
  }

  // ============ stage 2: l2norm over words, softmax over regions ============
  float* attnL = bufB;            // [36][25]
  if (tid < 36) {
    const int r = tid;
    float s = 0.f;
    for (int w = 0; w < 24; w++) { float x = attnL[r * 25 + w]; s += x * x; }
    const float inv = 1.f / (sqrtf(s) + EPSV);
    for (int w = 0; w < 24; w++) attnL[r * 25 + w] *= inv;
  }
  __syncthreads();
  float* attnW = bufA + 4752;     // [24][44] (CAP dead)
  if (tid < 24) {
    const int w = tid;
    float m = -1e30f;
    for (int r = 0; r < 36; r++) m = fmaxf(m, attnL[r * 25 + w]);
    float ssum = 0.f;
    for (int r = 0; r < 36; r++) {
      float e = expf(4.0f * (attnL[r * 25 + w] - m));
      attnW[w * 44 + r] = e; ssum += e;
    }
    const float inv = 1.0f / ssum;
    for (int r = 0; r < 36; r++) attnW[w * 44 + r] *= inv;
  }
  float* qnL = bufA + 5808;       // [24][32]
  for (int p = tid; p < 768; p += 256) qnL[p] = ws[WS_QN + c * 768 + p];
  // visibility: first __syncthreads inside stage-3 loop

  // ============ stage 3: register wctx + fused block-cosine -> tnode ============
  float* tnodeL = bufA + 6576;    // [24][36]
  const int g3 = tid >> 5, dq = tid & 31, w03 = g3 * 4;
  for (int k0 = 0; k0 < EMBED; k0 += 128) {
    __syncthreads();
    for (int idx = tid; idx < 1152; idx += 256) {   // IMG only
      const int r = idx >> 5, q = idx & 31;
      *(float4*)&IMG[r * 132 + q * 4] = *(const float4*)(imgN + r * EMBED + k0 + q * 4);
    }
    __syncthreads();
    if (tid < 192) {
      float4 ctx0 = make_float4(0.f, 0.f, 0.f, 0.f), ctx1 = ctx0, ctx2 = ctx0, ctx3 = ctx0;
      for (int rb = 0; rb < 36; rb += 4) {
        float4 iv0 = *(const float4*)&IMG[(rb + 0) * 132 + dq * 4];
        float4 iv1 = *(const float4*)&IMG[(rb + 1) * 132 + dq * 4];
        float4 iv2 = *(const float4*)&IMG[(rb + 2) * 132 + dq * 4];
        float4 iv3 = *(const float4*)&IMG[(rb + 3) * 132 + dq * 4];
        float4 a0 = *(const float4*)&attnW[(w03 + 0) * 44 + rb];
        float4 a1 = *(const float4*)&attnW[(w03 + 1) * 44 + rb];
        float4 a2 = *(const float4*)&attnW[(w03 + 2) * 44 + rb];
        float4 a3 = *(const float4*)&attnW[(w03 + 3) * 44 + rb];
        ctx0.x += a0.x * iv0.x + a0.y * iv1.x + a0.z * iv2.x + a0.w * iv3.x;
        ctx0.y += a0.x * iv0.y + a0.y * iv1.y + a0.z * iv2.y + a0.w * iv3.y;
        ctx0.z += a0.x * iv0.z + a0.y * iv1.z + a0.z * iv2.z + a0.w * iv3.z;
        ctx0.w += a0.x * iv0.w + a0.y * iv1.w + a0.z * iv2.w + a0.w * iv3.w;
        ctx1.x += a1.x * iv0.x + a1.y * iv1.x + a1.z * iv2.x + a1.w * iv3.x;
        ctx1.y += a1.x * iv0.y + a1.y * iv1.y + a1.z * iv2.y + a1.w * iv3.y;
        ctx1.z += a1.x * iv0.z + a1.y * iv1.z + a1.z * iv2.z + a1.w * iv3.z;
        ctx1.w += a1.x * iv0.w + a1.y * iv1.w + a1.z * iv2.w + a1.w * iv3.w;
        ctx2.x += a2.x * iv0.x + a2.y * iv1.x + a2.z * iv2.x + a2.w * iv3.x;
        ctx2.y += a2.x * iv0.y + a2.y * iv1.y + a2.z * iv2.y + a2.w * iv3.y;
        ctx2.z += a2.x * iv0.z + a2.y * iv1.z + a2.z * iv2.z + a2.w * iv3.z;
        ctx2.w += a2.x * iv0.w + a2.y * iv1.w + a2.z * iv2.w + a2.w * iv3.w;
        ctx3.x += a3.x * iv0.x + a3.y * iv1.x + a3.z * iv2.x + a3.w * iv3.x;
        ctx3.y += a3.x * iv0.y + a3.y * iv1.y + a3.z * iv2.y + a3.w * iv3.y;
        ctx3.z += a3.x * iv0.z + a3.y * iv1.z + a3.z * iv2.z + a3.w * iv3.z;
        ctx3.w += a3.x * iv0.w + a3.y * iv1.w + a3.z * iv2.w + a3.w * iv3.w;
      }
      // cosine partials: cap straight from global (L2-hot)
      float red[8];
      {
        float4 c4;
        c4 = *(const float4*)(capC + (w03 + 0) * EMBED + k0 + dq * 4);
        red[0] = c4.x * ctx0.x + c4.y * ctx0.y + c4.z * ctx0.z + c4.w * ctx0.w;
        red[4] = ctx0.x * ctx0.x + ctx0.y * ctx0.y + ctx0.z * ctx0.z + ctx0.w * ctx0.w;
        c4 = *(const float4*)(capC + (w03 + 1) * EMBED + k0 + dq * 4);
        red[1] = c4.x * ctx1.x + c4.y * ctx1.y + c4.z * ctx1.z + c4.w * ctx1.w;
        red[5] = ctx1.x * ctx1.x + ctx1.y * ctx1.y + ctx1.z * ctx1.z + ctx1.w * ctx1.w;
        c4 = *(const float4*)(capC + (w03 + 2) * EMBED + k0 + dq * 4);
        red[2] = c4.x * ctx2.x + c4.y * ctx2.y + c4.z * ctx2.z + c4.w * ctx2.w;
        red[6] = ctx2.x * ctx2.x + ctx2.y * ctx2.y + ctx2.z * ctx2.z + ctx2.w * ctx2.w;
        c4 = *(const float4*)(capC + (w03 + 3) * EMBED + k0 + dq * 4);
        red[3] = c4.x * ctx3.x + c4.y * ctx3.y + c4.z * ctx3.z + c4.w * ctx3.w;
        red[7] = ctx3.x * ctx3.x + ctx3.y * ctx3.y + ctx3.z * ctx3.z + ctx3.w * ctx3.w;
      }
      // butterfly over the 8-lane octet owning this (word-group, f-block)
#pragma unroll
      for (int m = 1; m < 8; m <<= 1) {
#pragma unroll
        for (int t = 0; t < 8; t++) red[t] += __shfl_xor(red[t], m);
      }
      if ((dq & 7) == 0) {
        const int f = (k0 >> 5) + (dq >> 3);
#pragma unroll
        for (int j = 0; j < 4; j++) {
          const float qn = qnL[(w03 + j) * 32 + f];
          tnodeL[(w03 + j) * 36 + f] = red[j] / fmaxf(qn * sqrtf(red[4 + j]), EPSV);
        }
      }
    }
  }
  __syncthreads();

  // ============ stage 4a: conv collapse -> hidden ============
  float* convT = bufA;            // [32 f][68]: convT[f][col], col=k*8+o (IMG dead)
  for (int idx = tid; idx < 2048; idx += 256) {
    const int f = idx >> 6, col = idx & 63;
    convT[f * 68 + col] = conv_w[(col >> 3) * 256 + f * 8 + (col & 7)];
  }
  float* w2s = bufB + 1632, * b1s = bufB + 1696, * Ss = bufB + 1760, * sred = bufB + 1952;
  for (int p = tid; p < 192; p += 256) Ss[p] = ws[WS_S + c * 192 + p];
  if (tid < 64) w2s[tid] = ws[WS_W2 + tid];
  else if (tid < 128) b1s[tid - 64] = out1_b[tid - 64];
  __syncthreads();

  float* hiddenL = bufB;          // [24][68] (attnL dead)
  {
    const int col = tid & 63, wg = tid >> 6;
    float cw[32];
#pragma unroll
    for (int f = 0; f < 32; f++) cw[f] = convT[f * 68 + col];
    const int kk = col >> 3;
#pragma unroll
    for (int rnd = 0; rnd < 6; rnd++) {
      const int w = wg * 6 + rnd;
      float a = 0.f;
#pragma unroll
      for (int f4 = 0; f4 < 8; f4++) {
        float4 t4 = *(const float4*)&tnodeL[w * 36 + f4 * 4];
        a += t4.x * cw[f4 * 4 + 0] + t4.y * cw[f4 * 4 + 1] +
             t4.z * cw[f4 * 4 + 2] + t4.w * cw[f4 * 4 + 3];
      }
      hiddenL[w * 68 + col] = Ss[w * 8 + kk] * a;
    }
  }
  __syncthreads();

  // ============ stage 4b: h = tanh(hidden @ W1^T + b1) ============
  float* W1t = bufA;              // [64 col][68]: W1t[col][j] (convT/tnode dead)
  for (int idx = tid; idx < 4096; idx += 256) {
    const int j = idx >> 6, col = idx & 63;
    W1t[col * 68 + j] = ws[WS_W1 + idx];
  }
  __syncthreads();
  float hv[2][4];
  {
    int pc = 0;
    for (int p = tid; p < 384; p += 256, pc++) {
      const int w = p >> 4, j0 = (p & 15) * 4;
      float ax = b1s[j0 + 0], ay = b1s[j0 + 1], az = b1s[j0 + 2], aww = b1s[j0 + 3];
      for (int col = 0; col < 64; col += 4) {
        float4 h4 = *(const float4*)&hiddenL[w * 68 + col];
        float4 wv0 = *(const float4*)&W1t[(col + 0) * 68 + j0];
        float4 wv1 = *(const float4*)&W1t[(col + 1) * 68 + j0];
        float4 wv2 = *(const float4*)&W1t[(col + 2) * 68 + j0];
        float4 wv3 = *(const float4*)&W1t[(col + 3) * 68 + j0];
        ax  += h4.x * wv0.x + h4.y * wv1.x + h4.z * wv2.x + h4.w * wv3.x;
        ay  += h4.x * wv0.y + h4.y * wv1.y + h4.z * wv2.y + h4.w * wv3.y;
        az  += h4.x * wv0.z + h4.y * wv1.z + h4.z * wv2.z + h4.w * wv3.z;
        aww += h4.x * wv0.w + h4.y * wv1.w + h4.z * wv2.w + h4.w * wv3.w;
      }
      hv[pc][0] = tanhf(ax); hv[pc][1] = tanhf(ay);
      hv[pc][2] = tanhf(az); hv[pc][3] = tanhf(aww);
    }
    __syncthreads();
    pc = 0;
    for (int p = tid; p < 384; p += 256, pc++) {
      const int w = p >> 4, j0 = (p & 15) * 4;
      hiddenL[w * 68 + j0 + 0] = hv[pc][0]; hiddenL[w * 68 + j0 + 1] = hv[pc][1];
      hiddenL[w * 68 + j0 + 2] = hv[pc][2]; hiddenL[w * 68 + j0 + 3] = hv[pc][3];
    }
    __syncthreads();
  }

  // s[w] = h[w]·w2 + b2; output = mean over words
  if (tid < 24) {
    const int w = tid;
    float sv = out2_b[0];
    for (int j = 0; j < 64; j++) sv += hiddenL[w * 68 + j] * w2s[j];
    sred[w] = sv;
  }
  __syncthreads();
  if (tid == 0) {
    float s = 0.f;
    for (int w = 0; w < 24; w++) s += sred[w];
    out[n * 32 + c] = s * (1.0f / 24.0f);
  }
}

// ---------------------------------------------------------------------------
extern "C" void kernel_launch(void* const* d_in, const int* in_sizes, int n_in,
                              void* d_out, int out_size, void* d_ws, size_t ws_size,
                              hipStream_t stream) {
  const float* images   = (const float*)d_in[0];
  const float* captions = (const float*)d_in[1];
  const int*   depends  = (const int*)d_in[2];
  // d_in[3] cap_lens: unused (all == N_WORD)
  const float* mean_k   = (const float*)d_in[4];
  const float* prec_k   = (const float*)d_in[5];
  const float* conv_w   = (const float*)d_in[6];
  const float* out1_v   = (const float*)d_in[7];
  const float* out1_g   = (const float*)d_in[8];
  const float* out1_b   = (const float*)d_in[9];
  const float* out2_v   = (const float*)d_in[10];
  const float* out2_g   = (const float*)d_in[11];
  const float* out2_b   = (const float*)d_in[12];
  float* ws  = (float*)d_ws;
  float* out = (float*)d_out;

  cap_prep_k<<<dim3(33), dim3(256), 0, stream>>>(
      captions, depends, mean_k, prec_k, out1_v, out1_g, out2_v, out2_g, ws);
  main_k<<<dim3(N_IMAGE * N_CAPTION), dim3(256), 0, stream>>>(
      images, captions, conv_w, out1_b, out2_b, ws, out);
}